// Round 6
// baseline (630.056 us; speedup 1.0000x reference)
//
#include <hip/hip_runtime.h>
#include <math.h>

#define IN_F 64
#define HID 128
#define NCLS 10

// ---------- degree histogram over targets ----------
__global__ void k_hist(const int* __restrict__ col, int* __restrict__ cnt, int E) {
    int i = blockIdx.x * blockDim.x + threadIdx.x;
    if (i < E) atomicAdd(&cnt[col[i]], 1);
}

// ---------- 3-kernel exclusive scan (cnt -> rowptr) ----------
__global__ void k_blocksum(const int* __restrict__ cnt, int* __restrict__ bsum, int n) {
    __shared__ int s[256];
    int i = blockIdx.x * 256 + threadIdx.x;
    s[threadIdx.x] = (i < n) ? cnt[i] : 0;
    __syncthreads();
    for (int off = 128; off > 0; off >>= 1) {
        if (threadIdx.x < off) s[threadIdx.x] += s[threadIdx.x + off];
        __syncthreads();
    }
    if (threadIdx.x == 0) bsum[blockIdx.x] = s[0];
}

__global__ void k_scan_bsum(const int* __restrict__ bsum, int* __restrict__ boff, int nb,
                            int* __restrict__ rowptr, int n, int E) {
    __shared__ int s[512];
    int t = threadIdx.x;
    int v = (t < nb) ? bsum[t] : 0;
    s[t] = v;
    __syncthreads();
    for (int off = 1; off < 512; off <<= 1) {
        int tmp = (t >= off) ? s[t - off] : 0;
        __syncthreads();
        s[t] += tmp;
        __syncthreads();
    }
    if (t < nb) boff[t] = s[t] - v;  // exclusive
    if (t == 0) rowptr[n] = E;
}

// scan within block + write rowptr, pos (=rowptr copy), dis — fused
__global__ void k_scan_final(const int* __restrict__ cnt, const int* __restrict__ boff,
                             int* __restrict__ rowptr, int* __restrict__ pos,
                             float* __restrict__ dis, int n) {
    __shared__ int s[256];
    int i = blockIdx.x * 256 + threadIdx.x;
    int v = (i < n) ? cnt[i] : 0;
    s[threadIdx.x] = v;
    __syncthreads();
    for (int off = 1; off < 256; off <<= 1) {
        int tmp = (threadIdx.x >= off) ? s[threadIdx.x - off] : 0;
        __syncthreads();
        s[threadIdx.x] += tmp;
        __syncthreads();
    }
    if (i < n) {
        int rp = boff[blockIdx.x] + s[threadIdx.x] - v;  // exclusive
        rowptr[i] = rp;
        pos[i] = rp;
        dis[i] = rsqrtf(1.0f + (float)v);
    }
}

// ---------- CSR fill: src list sorted by target ----------
__global__ void k_fill(const int* __restrict__ row, const int* __restrict__ col,
                       int* __restrict__ pos, int* __restrict__ src, int E) {
    int e = blockIdx.x * blockDim.x + threadIdx.x;
    if (e >= E) return;
    int p = atomicAdd(&pos[col[e]], 1);
    src[p] = row[e];
}

// ---------- xs = x * dis[node] (fp32) ----------
__global__ void k_xs(const float* __restrict__ x, const float* __restrict__ dis,
                     float* __restrict__ xs, int n16) {
    int i = blockIdx.x * blockDim.x + threadIdx.x;
    if (i >= n16) return;
    float d = dis[i >> 4];  // 16 float4s per node (64 feats)
    float4 v = ((const float4*)x)[i];
    v.x *= d; v.y *= d; v.z *= d; v.w *= d;
    ((float4*)xs)[i] = v;
}

// ---------- fused gather1 + GEMM1 + relu + GEMM2 (h2s) ----------
// gather: one wave per node; 16 lanes x float4 per row; 4 edge slots, x2 unroll
//         => 8 independent 256B row-loads in flight per wave (R3-proven config)
// epilogue: GEMM1 via LDS broadcast, relu -> LDS, then quarter-wave x class
//           mapping computes h2s[i,c] = dis[i] * sum_k relu(h)[k] W2[k,c]
__global__ __launch_bounds__(256) void k_l1(const float* __restrict__ xs,
                                            const int* __restrict__ src,
                                            const int* __restrict__ rowptr,
                                            const float* __restrict__ dis,
                                            const float* __restrict__ W1,
                                            const float* __restrict__ b1,
                                            const float* __restrict__ W2,
                                            float* __restrict__ h2s, int n) {
    __shared__ float hacc[4][64];
    __shared__ float hrelu[4][HID];
    int w = threadIdx.x >> 6, lane = threadIdx.x & 63;
    int q = lane >> 4;      // edge slot 0..3
    int f4 = lane & 15;     // float4 chunk within the 64-float row
    int i = blockIdx.x * 4 + w;
    float4 acc = make_float4(0.f, 0.f, 0.f, 0.f);
    float d = 0.f;
    if (i < n) {
        d = dis[i];
        if (q == 0)  // self-loop term counted once
            acc = ((const float4*)(xs + (size_t)i * IN_F))[f4];
        int end = rowptr[i + 1];
        int e = rowptr[i] + q;
        for (; e + 4 < end; e += 8) {
            int s0 = src[e];
            int s1 = src[e + 4];
            float4 v0 = ((const float4*)(xs + (size_t)s0 * IN_F))[f4];
            float4 v1 = ((const float4*)(xs + (size_t)s1 * IN_F))[f4];
            acc.x += v0.x + v1.x;
            acc.y += v0.y + v1.y;
            acc.z += v0.z + v1.z;
            acc.w += v0.w + v1.w;
        }
        if (e < end) {
            int s = src[e];
            float4 v = ((const float4*)(xs + (size_t)s * IN_F))[f4];
            acc.x += v.x;
            acc.y += v.y;
            acc.z += v.z;
            acc.w += v.w;
        }
    }
    // combine the 4 edge slots: xor butterfly over lane bits 4 and 5
    acc.x += __shfl_xor(acc.x, 16, 64);
    acc.y += __shfl_xor(acc.y, 16, 64);
    acc.z += __shfl_xor(acc.z, 16, 64);
    acc.w += __shfl_xor(acc.w, 16, 64);
    acc.x += __shfl_xor(acc.x, 32, 64);
    acc.y += __shfl_xor(acc.y, 32, 64);
    acc.z += __shfl_xor(acc.z, 32, 64);
    acc.w += __shfl_xor(acc.w, 32, 64);
    if (q == 0) {
        acc.x *= d; acc.y *= d; acc.z *= d; acc.w *= d;
        ((float4*)&hacc[w][f4 * 4])[0] = acc;
    }
    __syncthreads();
    if (i < n) {
        // GEMM1: columns 2*lane, 2*lane+1
        float2 bv = ((const float2*)b1)[lane];
        float h0 = bv.x, h1 = bv.y;
#pragma unroll
        for (int k = 0; k < IN_F; ++k) {
            float a = hacc[w][k];  // LDS broadcast
            float2 wv = ((const float2*)(W1 + k * HID))[lane];
            h0 = fmaf(a, wv.x, h0);
            h1 = fmaf(a, wv.y, h1);
        }
        hrelu[w][2 * lane] = fmaxf(h0, 0.f);
        hrelu[w][2 * lane + 1] = fmaxf(h1, 0.f);
        // wave-local LDS: same wave writes then reads hrelu[w] — no barrier needed
        // GEMM2: lane = kq*16 + c ; kq = k-quarter (32 k's), c = class (0..9 live)
        int kq = lane >> 4;
        int c = lane & 15;
        int cw = (c < NCLS) ? c : 0;  // clamp to keep W2 reads in bounds
        float acc2 = 0.f;
#pragma unroll
        for (int kk = 0; kk < 32; ++kk) {
            int kr = (kk + 8 * kq) & 31;  // stagger start per quarter: 4 banks/read
            int k = 32 * kq + kr;
            acc2 = fmaf(hrelu[w][k], W2[k * NCLS + cw], acc2);
        }
        acc2 += __shfl_xor(acc2, 16, 64);
        acc2 += __shfl_xor(acc2, 32, 64);
        if (kq == 0 && c < NCLS) h2s[(size_t)i * NCLS + c] = acc2 * d;
    }
}

// ---------- fused gather2 + b2 + log-softmax + mean-reduce (fp32, R3) ----------
__global__ void k_lsm2(const float* __restrict__ h2s, const int* __restrict__ src,
                       const int* __restrict__ rowptr, const float* __restrict__ dis,
                       const float* __restrict__ b2, float* __restrict__ out, int n,
                       float inv_n) {
    __shared__ float sred[NCLS];
    if (threadIdx.x < NCLS) sred[threadIdx.x] = 0.f;
    __syncthreads();
    int i = blockIdx.x * blockDim.x + threadIdx.x;
    float loc[NCLS];
#pragma unroll
    for (int c = 0; c < NCLS; ++c) loc[c] = 0.f;
    if (i < n) {
        float a[NCLS], a2[NCLS];
        const float* self = h2s + (size_t)i * NCLS;
#pragma unroll
        for (int c = 0; c < NCLS; c += 2) {
            float2 v = *(const float2*)(self + c);
            a[c] = v.x;
            a[c + 1] = v.y;
            a2[c] = 0.f;
            a2[c + 1] = 0.f;
        }
        int beg = rowptr[i], end = rowptr[i + 1];
        int e = beg;
        for (; e + 1 < end; e += 2) {  // 2 independent accumulator chains
            const float* p0 = h2s + (size_t)src[e] * NCLS;
            const float* p1 = h2s + (size_t)src[e + 1] * NCLS;
#pragma unroll
            for (int c = 0; c < NCLS; c += 2) {
                float2 v0 = *(const float2*)(p0 + c);
                float2 v1 = *(const float2*)(p1 + c);
                a[c] += v0.x;
                a[c + 1] += v0.y;
                a2[c] += v1.x;
                a2[c + 1] += v1.y;
            }
        }
        if (e < end) {
            const float* p = h2s + (size_t)src[e] * NCLS;
#pragma unroll
            for (int c = 0; c < NCLS; c += 2) {
                float2 v = *(const float2*)(p + c);
                a[c] += v.x;
                a[c + 1] += v.y;
            }
        }
        float d = dis[i];
        float vv[NCLS];
        float m = -1e30f;
#pragma unroll
        for (int c = 0; c < NCLS; ++c) {
            vv[c] = b2[c] + d * (a[c] + a2[c]);
            m = fmaxf(m, vv[c]);
        }
        float se = 0.f;
#pragma unroll
        for (int c = 0; c < NCLS; ++c) se += __expf(vv[c] - m);
        float lse = m + __logf(se);
#pragma unroll
        for (int c = 0; c < NCLS; ++c) loc[c] = vv[c] - lse;
    }
#pragma unroll
    for (int c = 0; c < NCLS; ++c) atomicAdd(&sred[c], loc[c]);
    __syncthreads();
    if (threadIdx.x < NCLS) atomicAdd(&out[threadIdx.x], sred[threadIdx.x] * inv_n);
}

extern "C" void kernel_launch(void* const* d_in, const int* in_sizes, int n_in,
                              void* d_out, int out_size, void* d_ws, size_t ws_size,
                              hipStream_t stream) {
    const float* x = (const float*)d_in[0];
    const int* eidx = (const int*)d_in[1];
    const float* W1 = (const float*)d_in[2];
    const float* b1 = (const float*)d_in[3];
    const float* W2 = (const float*)d_in[4];
    const float* b2 = (const float*)d_in[5];
    float* out = (float*)d_out;

    const int N = in_sizes[0] / IN_F;  // 100000
    const int E = in_sizes[1] / 2;     // 1600000
    const int* row = eidx;             // sources
    const int* col = eidx + E;         // targets

    const int NB = (N + 255) / 256;  // scan blocks (391 <= 512)

    // workspace layout (4-byte words, 1024-word aligned)
    size_t o = 0;
    auto alloc = [&](size_t words) {
        size_t r = o;
        o += (words + 1023) & ~(size_t)1023;
        return r;
    };
    float* ws = (float*)d_ws;
    float* dis = ws + alloc(N);
    float* xs = ws + alloc((size_t)N * IN_F);
    float* h2s = ws + alloc((size_t)N * NCLS);
    int* src = (int*)(ws + alloc(E));
    int* rowptr = (int*)(ws + alloc(N + 1));
    int* cnt = (int*)(ws + alloc(N));
    int* pos = (int*)(ws + alloc(N));
    int* bsum = (int*)(ws + alloc(1024));
    int* boff = (int*)(ws + alloc(1024));

    const int B = 256;

    // ---- CSR build + degrees ----
    hipMemsetAsync(cnt, 0, (size_t)N * sizeof(int), stream);
    k_hist<<<(E + B - 1) / B, B, 0, stream>>>(col, cnt, E);
    k_blocksum<<<NB, 256, 0, stream>>>(cnt, bsum, N);
    k_scan_bsum<<<1, 512, 0, stream>>>(bsum, boff, NB, rowptr, N, E);
    k_scan_final<<<NB, 256, 0, stream>>>(cnt, boff, rowptr, pos, dis, N);
    k_fill<<<(E + B - 1) / B, B, 0, stream>>>(row, col, pos, src, E);

    // ---- layer 1 aggregate + GEMM1 + relu + GEMM2 (writes h2s) ----
    k_xs<<<(N * 16 + B - 1) / B, B, 0, stream>>>(x, dis, xs, N * 16);
    k_l1<<<(N + 3) / 4, 256, 0, stream>>>(xs, src, rowptr, dis, W1, b1, W2, h2s, N);

    // ---- layer 2 aggregate + log-softmax + mean ----
    hipMemsetAsync(out, 0, NCLS * sizeof(float), stream);
    k_lsm2<<<NB, 256, 0, stream>>>(h2s, src, rowptr, dis, b2, out, N, 1.0f / (float)N);
}

// Round 7
// 522.193 us; speedup vs baseline: 1.2066x; 1.2066x over previous
//
#include <hip/hip_runtime.h>
#include <math.h>

#define IN_F 64
#define HID 128
#define NCLS 10
#define H2S_STRIDE 16  // padded h2s row (64 B) -> one cache line per gather

// ---------- degree histogram over targets ----------
__global__ void k_hist(const int* __restrict__ col, int* __restrict__ cnt, int E) {
    int i = blockIdx.x * blockDim.x + threadIdx.x;
    if (i < E) atomicAdd(&cnt[col[i]], 1);
}

// ---------- 3-kernel exclusive scan (cnt -> rowptr) ----------
__global__ void k_blocksum(const int* __restrict__ cnt, int* __restrict__ bsum, int n) {
    __shared__ int s[256];
    int i = blockIdx.x * 256 + threadIdx.x;
    s[threadIdx.x] = (i < n) ? cnt[i] : 0;
    __syncthreads();
    for (int off = 128; off > 0; off >>= 1) {
        if (threadIdx.x < off) s[threadIdx.x] += s[threadIdx.x + off];
        __syncthreads();
    }
    if (threadIdx.x == 0) bsum[blockIdx.x] = s[0];
}

__global__ void k_scan_bsum(const int* __restrict__ bsum, int* __restrict__ boff, int nb,
                            int* __restrict__ rowptr, int n, int E) {
    __shared__ int s[512];
    int t = threadIdx.x;
    int v = (t < nb) ? bsum[t] : 0;
    s[t] = v;
    __syncthreads();
    for (int off = 1; off < 512; off <<= 1) {
        int tmp = (t >= off) ? s[t - off] : 0;
        __syncthreads();
        s[t] += tmp;
        __syncthreads();
    }
    if (t < nb) boff[t] = s[t] - v;  // exclusive
    if (t == 0) rowptr[n] = E;
}

// scan within block + write rowptr, pos (=rowptr copy), dis — fused
__global__ void k_scan_final(const int* __restrict__ cnt, const int* __restrict__ boff,
                             int* __restrict__ rowptr, int* __restrict__ pos,
                             float* __restrict__ dis, int n) {
    __shared__ int s[256];
    int i = blockIdx.x * 256 + threadIdx.x;
    int v = (i < n) ? cnt[i] : 0;
    s[threadIdx.x] = v;
    __syncthreads();
    for (int off = 1; off < 256; off <<= 1) {
        int tmp = (threadIdx.x >= off) ? s[threadIdx.x - off] : 0;
        __syncthreads();
        s[threadIdx.x] += tmp;
        __syncthreads();
    }
    if (i < n) {
        int rp = boff[blockIdx.x] + s[threadIdx.x] - v;  // exclusive
        rowptr[i] = rp;
        pos[i] = rp;
        dis[i] = rsqrtf(1.0f + (float)v);
    }
}

// ---------- CSR fill: src list sorted by target ----------
__global__ void k_fill(const int* __restrict__ row, const int* __restrict__ col,
                       int* __restrict__ pos, int* __restrict__ src, int E) {
    int e = blockIdx.x * blockDim.x + threadIdx.x;
    if (e >= E) return;
    int p = atomicAdd(&pos[col[e]], 1);
    src[p] = row[e];
}

// ---------- xs = x * dis[node] (fp32) ----------
__global__ void k_xs(const float* __restrict__ x, const float* __restrict__ dis,
                     float* __restrict__ xs, int n16) {
    int i = blockIdx.x * blockDim.x + threadIdx.x;
    if (i >= n16) return;
    float d = dis[i >> 4];  // 16 float4s per node (64 feats)
    float4 v = ((const float4*)x)[i];
    v.x *= d; v.y *= d; v.z *= d; v.w *= d;
    ((float4*)xs)[i] = v;
}

// ---------- fused gather1 + GEMM1 + bias + relu (R3 structure, unroll x4) ----------
// one wave per node; 16 lanes x float4 per row; 4 edge slots, x4 unroll
// => 16 edges (4 loads/lane) in flight per wave
__global__ __launch_bounds__(256) void k_l1(const float* __restrict__ xs,
                                            const int* __restrict__ src,
                                            const int* __restrict__ rowptr,
                                            const float* __restrict__ dis,
                                            const float* __restrict__ W1,
                                            const float* __restrict__ b1,
                                            float* __restrict__ h, int n) {
    __shared__ float hacc[4][64];
    int w = threadIdx.x >> 6, lane = threadIdx.x & 63;
    int q = lane >> 4;      // edge slot 0..3
    int f4 = lane & 15;     // float4 chunk within the 64-float row
    int i = blockIdx.x * 4 + w;
    float4 acc = make_float4(0.f, 0.f, 0.f, 0.f);
    float d = 0.f;
    if (i < n) {
        d = dis[i];
        if (q == 0)  // self-loop term counted once
            acc = ((const float4*)(xs + (size_t)i * IN_F))[f4];
        int end = rowptr[i + 1];
        int e = rowptr[i] + q;
        for (; e + 12 < end; e += 16) {
            int s0 = src[e];
            int s1 = src[e + 4];
            int s2 = src[e + 8];
            int s3 = src[e + 12];
            float4 v0 = ((const float4*)(xs + (size_t)s0 * IN_F))[f4];
            float4 v1 = ((const float4*)(xs + (size_t)s1 * IN_F))[f4];
            float4 v2 = ((const float4*)(xs + (size_t)s2 * IN_F))[f4];
            float4 v3 = ((const float4*)(xs + (size_t)s3 * IN_F))[f4];
            acc.x += (v0.x + v1.x) + (v2.x + v3.x);
            acc.y += (v0.y + v1.y) + (v2.y + v3.y);
            acc.z += (v0.z + v1.z) + (v2.z + v3.z);
            acc.w += (v0.w + v1.w) + (v2.w + v3.w);
        }
        for (; e < end; e += 4) {  // up to 3 tail edges per slot
            int s = src[e];
            float4 v = ((const float4*)(xs + (size_t)s * IN_F))[f4];
            acc.x += v.x;
            acc.y += v.y;
            acc.z += v.z;
            acc.w += v.w;
        }
    }
    // combine the 4 edge slots: xor butterfly over lane bits 4 and 5
    acc.x += __shfl_xor(acc.x, 16, 64);
    acc.y += __shfl_xor(acc.y, 16, 64);
    acc.z += __shfl_xor(acc.z, 16, 64);
    acc.w += __shfl_xor(acc.w, 16, 64);
    acc.x += __shfl_xor(acc.x, 32, 64);
    acc.y += __shfl_xor(acc.y, 32, 64);
    acc.z += __shfl_xor(acc.z, 32, 64);
    acc.w += __shfl_xor(acc.w, 32, 64);
    if (q == 0) {
        acc.x *= d; acc.y *= d; acc.z *= d; acc.w *= d;
        ((float4*)&hacc[w][f4 * 4])[0] = acc;
    }
    __syncthreads();
    if (i < n) {
        float h0 = b1[lane], h1 = b1[lane + 64];
#pragma unroll
        for (int k = 0; k < IN_F; ++k) {
            float a = hacc[w][k];  // LDS broadcast
            h0 = fmaf(a, W1[k * HID + lane], h0);
            h1 = fmaf(a, W1[k * HID + lane + 64], h1);
        }
        h[(size_t)i * HID + lane] = fmaxf(h0, 0.f);
        h[(size_t)i * HID + lane + 64] = fmaxf(h1, 0.f);
    }
}

// ---------- h2s[i*16+c] = dis[i] * sum_k h[i,k] W2[k,c] ----------
__global__ void k_h2s(const float* __restrict__ h, const float* __restrict__ W2,
                      const float* __restrict__ dis, float* __restrict__ h2s, int n) {
    int idx = blockIdx.x * blockDim.x + threadIdx.x;
    if (idx >= n * NCLS) return;
    int node = idx / NCLS;
    int c = idx - node * NCLS;
    const float* hr = h + (size_t)node * HID;
    float acc = 0.f;
#pragma unroll
    for (int k = 0; k < HID; k += 4) {
        float4 hv = *(const float4*)(hr + k);
        acc = fmaf(hv.x, W2[(k + 0) * NCLS + c], acc);
        acc = fmaf(hv.y, W2[(k + 1) * NCLS + c], acc);
        acc = fmaf(hv.z, W2[(k + 2) * NCLS + c], acc);
        acc = fmaf(hv.w, W2[(k + 3) * NCLS + c], acc);
    }
    h2s[(size_t)node * H2S_STRIDE + c] = acc * dis[node];
}

// ---------- fused gather2 + b2 + log-softmax + mean-reduce ----------
__global__ void k_lsm2(const float* __restrict__ h2s, const int* __restrict__ src,
                       const int* __restrict__ rowptr, const float* __restrict__ dis,
                       const float* __restrict__ b2, float* __restrict__ out, int n,
                       float inv_n) {
    __shared__ float sred[NCLS];
    if (threadIdx.x < NCLS) sred[threadIdx.x] = 0.f;
    __syncthreads();
    int i = blockIdx.x * blockDim.x + threadIdx.x;
    float loc[NCLS];
#pragma unroll
    for (int c = 0; c < NCLS; ++c) loc[c] = 0.f;
    if (i < n) {
        float a[NCLS], a2[NCLS];
        const float* self = h2s + (size_t)i * H2S_STRIDE;
        {
            float4 v0 = *(const float4*)(self);
            float4 v1 = *(const float4*)(self + 4);
            float2 v2 = *(const float2*)(self + 8);
            a[0] = v0.x; a[1] = v0.y; a[2] = v0.z; a[3] = v0.w;
            a[4] = v1.x; a[5] = v1.y; a[6] = v1.z; a[7] = v1.w;
            a[8] = v2.x; a[9] = v2.y;
#pragma unroll
            for (int c = 0; c < NCLS; ++c) a2[c] = 0.f;
        }
        int beg = rowptr[i], end = rowptr[i + 1];
        int e = beg;
        for (; e + 1 < end; e += 2) {  // 2 independent accumulator chains
            const float* p0 = h2s + (size_t)src[e] * H2S_STRIDE;
            const float* p1 = h2s + (size_t)src[e + 1] * H2S_STRIDE;
            float4 u0 = *(const float4*)(p0);
            float4 u1 = *(const float4*)(p0 + 4);
            float2 u2 = *(const float2*)(p0 + 8);
            float4 w0 = *(const float4*)(p1);
            float4 w1 = *(const float4*)(p1 + 4);
            float2 w2 = *(const float2*)(p1 + 8);
            a[0] += u0.x; a[1] += u0.y; a[2] += u0.z; a[3] += u0.w;
            a[4] += u1.x; a[5] += u1.y; a[6] += u1.z; a[7] += u1.w;
            a[8] += u2.x; a[9] += u2.y;
            a2[0] += w0.x; a2[1] += w0.y; a2[2] += w0.z; a2[3] += w0.w;
            a2[4] += w1.x; a2[5] += w1.y; a2[6] += w1.z; a2[7] += w1.w;
            a2[8] += w2.x; a2[9] += w2.y;
        }
        if (e < end) {
            const float* p = h2s + (size_t)src[e] * H2S_STRIDE;
            float4 u0 = *(const float4*)(p);
            float4 u1 = *(const float4*)(p + 4);
            float2 u2 = *(const float2*)(p + 8);
            a[0] += u0.x; a[1] += u0.y; a[2] += u0.z; a[3] += u0.w;
            a[4] += u1.x; a[5] += u1.y; a[6] += u1.z; a[7] += u1.w;
            a[8] += u2.x; a[9] += u2.y;
        }
        float d = dis[i];
        float vv[NCLS];
        float m = -1e30f;
#pragma unroll
        for (int c = 0; c < NCLS; ++c) {
            vv[c] = b2[c] + d * (a[c] + a2[c]);
            m = fmaxf(m, vv[c]);
        }
        float se = 0.f;
#pragma unroll
        for (int c = 0; c < NCLS; ++c) se += __expf(vv[c] - m);
        float lse = m + __logf(se);
#pragma unroll
        for (int c = 0; c < NCLS; ++c) loc[c] = vv[c] - lse;
    }
#pragma unroll
    for (int c = 0; c < NCLS; ++c) atomicAdd(&sred[c], loc[c]);
    __syncthreads();
    if (threadIdx.x < NCLS) atomicAdd(&out[threadIdx.x], sred[threadIdx.x] * inv_n);
}

extern "C" void kernel_launch(void* const* d_in, const int* in_sizes, int n_in,
                              void* d_out, int out_size, void* d_ws, size_t ws_size,
                              hipStream_t stream) {
    const float* x = (const float*)d_in[0];
    const int* eidx = (const int*)d_in[1];
    const float* W1 = (const float*)d_in[2];
    const float* b1 = (const float*)d_in[3];
    const float* W2 = (const float*)d_in[4];
    const float* b2 = (const float*)d_in[5];
    float* out = (float*)d_out;

    const int N = in_sizes[0] / IN_F;  // 100000
    const int E = in_sizes[1] / 2;     // 1600000
    const int* row = eidx;             // sources
    const int* col = eidx + E;         // targets

    const int NB = (N + 255) / 256;  // scan blocks (391 <= 512)

    // workspace layout (4-byte words, 1024-word aligned)
    size_t o = 0;
    auto alloc = [&](size_t words) {
        size_t r = o;
        o += (words + 1023) & ~(size_t)1023;
        return r;
    };
    float* ws = (float*)d_ws;
    float* dis = ws + alloc(N);
    float* xs = ws + alloc((size_t)N * IN_F);
    float* h = ws + alloc((size_t)N * HID);
    float* h2s = ws + alloc((size_t)N * H2S_STRIDE);
    int* src = (int*)(ws + alloc(E));
    int* rowptr = (int*)(ws + alloc(N + 1));
    int* cnt = (int*)(ws + alloc(N));
    int* pos = (int*)(ws + alloc(N));
    int* bsum = (int*)(ws + alloc(1024));
    int* boff = (int*)(ws + alloc(1024));

    const int B = 256;

    // ---- CSR build + degrees ----
    hipMemsetAsync(cnt, 0, (size_t)N * sizeof(int), stream);
    k_hist<<<(E + B - 1) / B, B, 0, stream>>>(col, cnt, E);
    k_blocksum<<<NB, 256, 0, stream>>>(cnt, bsum, N);
    k_scan_bsum<<<1, 512, 0, stream>>>(bsum, boff, NB, rowptr, N, E);
    k_scan_final<<<NB, 256, 0, stream>>>(cnt, boff, rowptr, pos, dis, N);
    k_fill<<<(E + B - 1) / B, B, 0, stream>>>(row, col, pos, src, E);

    // ---- layer 1 (aggregate xs, then transform) ----
    k_xs<<<(N * 16 + B - 1) / B, B, 0, stream>>>(x, dis, xs, N * 16);
    k_l1<<<(N + 3) / 4, 256, 0, stream>>>(xs, src, rowptr, dis, W1, b1, h, N);

    // ---- layer 2 transform (pre-scaled messages, padded rows) ----
    k_h2s<<<(N * NCLS + B - 1) / B, B, 0, stream>>>(h, W2, dis, h2s, N);

    // ---- layer 2 aggregate + log-softmax + mean ----
    hipMemsetAsync(out, 0, NCLS * sizeof(float), stream);
    k_lsm2<<<NB, 256, 0, stream>>>(h2s, src, rowptr, dis, b2, out, N, 1.0f / (float)N);
}